// Round 3
// baseline (161.127 us; speedup 1.0000x reference)
//
#include <hip/hip_runtime.h>
#include <hip/hip_bf16.h>

// FeatureEmbedding: out[b, f+1, e] = sum_d relu(x[b,f]*W1[f,d]+b1[f,d]) * W2[f,d,e] + b2[f,e]
//                   out[b, 0,   e] = cls_token[e]
// B=4096, F=64, D=256. Output f32 [4096][65][256].

#define B_  4096
#define F_  64
#define D_  256
#define ORS (65 * 256)   // out row stride (floats)

using f32x4  = __attribute__((ext_vector_type(4))) float;
using s16x8  = __attribute__((ext_vector_type(8))) short;

__device__ __forceinline__ unsigned short to_bf16_bits(float v) {
    __hip_bfloat16 h = __float2bfloat16(v);
    return *reinterpret_cast<unsigned short*>(&h);
}

// ---------------------------------------------------------------------------
// Prep: W2 f32 [f][k][e] -> W2t bf16 [f][n=e][k] (k contiguous, 256 per row).
// f = bid&63 so prep writes land on the same XCD's L2 that main reads from.
// ---------------------------------------------------------------------------
__global__ __launch_bounds__(256) void femb_prep(
    const float* __restrict__ W2, unsigned short* __restrict__ W2t)
{
    const int f  = blockIdx.x & 63;
    const int kb = blockIdx.x >> 6;   // 0..3, 64 k each
    const int t  = threadIdx.x;       // owns output column n = t

    const float* col = W2 + (size_t)f * D_ * D_ + (size_t)(kb * 64) * D_ + t;
    float r[64];
    #pragma unroll
    for (int j = 0; j < 64; ++j) r[j] = col[(size_t)j * D_];

    unsigned short* ob = W2t + (size_t)f * 65536 + t * 256 + kb * 64;
    #pragma unroll
    for (int j8 = 0; j8 < 8; ++j8) {
        union { s16x8 s; unsigned short u[8]; } pk;
        #pragma unroll
        for (int e = 0; e < 8; ++e) pk.u[e] = to_bf16_bits(r[j8 * 8 + e]);
        *reinterpret_cast<s16x8*>(ob + j8 * 8) = pk.s;
    }
}

// ---------------------------------------------------------------------------
// Main: one block = (feature, 64-row tile). 256 threads = 4 waves (2 wm x 2 wn).
// Wave tile 32x128. B-fragments read straight from L2-resident W2t (no LDS
// staging, no K-loop barriers), software-pipelined 2 deep. Epilogue transposes
// through LDS so each global store writes one contiguous 1KB output row,
// nontemporal (out is never re-read; keep L2 for W2t).
// ---------------------------------------------------------------------------
__global__ __launch_bounds__(256, 2) void femb_main3(
    const float* __restrict__ x,  const float* __restrict__ W1,
    const float* __restrict__ b1, const unsigned short* __restrict__ W2t,
    const float* __restrict__ b2, float* __restrict__ out)
{
    __shared__ float w1s[D_];
    __shared__ float b1s[D_];
    __shared__ float xs[64];
    __shared__ __align__(16) float eb[32 * 260];  // 32 rows x 256 cols, stride 260

    const int tid  = threadIdx.x;
    const int bid  = blockIdx.x;
    const int f    = bid & 63;        // same-f blocks -> same XCD (L2 reuse of W2t_f)
    const int row0 = (bid >> 6) << 6; // 64 row-tiles of 64

    w1s[tid] = W1[f * D_ + tid];
    b1s[tid] = b1[f * D_ + tid];
    if (tid < 64) xs[tid] = x[(size_t)(row0 + tid) * F_ + f];

    const int lane = tid & 63;
    const int wid  = tid >> 6;
    const int wm   = wid >> 1;   // 0..1: row half (32 rows)
    const int wn   = wid & 1;    // 0..1: col half (128 cols)
    const int llo  = lane & 15;
    const int lhi  = lane >> 4;

    __syncthreads();

    float xv[2];
    #pragma unroll
    for (int mt = 0; mt < 2; ++mt) xv[mt] = xs[wm * 32 + mt * 16 + llo];

    f32x4 acc[2][8];
    #pragma unroll
    for (int mt = 0; mt < 2; ++mt)
        #pragma unroll
        for (int nt = 0; nt < 8; ++nt)
            acc[mt][nt] = (f32x4){0.f, 0.f, 0.f, 0.f};

    // Per-lane base into W2t: row n = wn*128 + nt*16 + llo, k-slice lhi*8.
    // Per (nt,ksg): offset nt*4096 + ksg*32 shorts. lhi*8 gives 4 consecutive
    // 16B slices per llo -> 64B L2 granules fully used.
    const unsigned short* bbase = W2t + (size_t)f * 65536
                                + (size_t)(wn * 128 + llo) * 256 + lhi * 8;

#define LOADB(BUF, KSG)                                                        \
    {                                                                          \
        _Pragma("unroll")                                                      \
        for (int nt = 0; nt < 8; ++nt)                                         \
            BUF[nt] = *reinterpret_cast<const s16x8*>(bbase + nt * 4096 + (KSG) * 32); \
    }

#define COMP(BUF, KSG)                                                         \
    {                                                                          \
        const int kg = (KSG) * 32 + lhi * 8;                                   \
        float w1r[8], b1r[8];                                                  \
        _Pragma("unroll")                                                      \
        for (int e = 0; e < 8; ++e) { w1r[e] = w1s[kg + e]; b1r[e] = b1s[kg + e]; } \
        s16x8 afrag[2];                                                        \
        _Pragma("unroll")                                                      \
        for (int mt = 0; mt < 2; ++mt) {                                       \
            union { s16x8 s; unsigned short u[8]; } pk;                        \
            _Pragma("unroll")                                                  \
            for (int e = 0; e < 8; ++e) {                                      \
                float h = fmaf(xv[mt], w1r[e], b1r[e]);                        \
                pk.u[e] = to_bf16_bits(fmaxf(h, 0.f));                         \
            }                                                                  \
            afrag[mt] = pk.s;                                                  \
        }                                                                      \
        _Pragma("unroll")                                                      \
        for (int nt = 0; nt < 8; ++nt)                                         \
            _Pragma("unroll")                                                  \
            for (int mt = 0; mt < 2; ++mt)                                     \
                acc[mt][nt] = __builtin_amdgcn_mfma_f32_16x16x32_bf16(         \
                    BUF[nt], afrag[mt], acc[mt][nt], 0, 0, 0);                 \
    }

    s16x8 bufA[8], bufB[8];
    LOADB(bufA, 0);
    #pragma unroll
    for (int kp = 0; kp < 4; ++kp) {
        LOADB(bufB, 2 * kp + 1);
        COMP(bufA, 2 * kp);
        if (kp < 3) LOADB(bufA, 2 * kp + 2);
        COMP(bufB, 2 * kp + 1);
    }
#undef LOADB
#undef COMP

    // Epilogue: 2 chunks of 32 rows. acc lane layout (swapped mfma, verified):
    // row = wm*32 + mt*16 + llo ; col = wn*128 + nt*16 + lhi*4 + r.
    // Transpose through LDS so each global store = one contiguous 1KB row.
    f32x4 b2v = *reinterpret_cast<const f32x4*>(&b2[f * D_ + lane * 4]);

    #pragma unroll
    for (int c = 0; c < 2; ++c) {
        if (wm == c) {
            #pragma unroll
            for (int mt = 0; mt < 2; ++mt) {
                const int lr = mt * 16 + llo;
                #pragma unroll
                for (int nt = 0; nt < 8; ++nt) {
                    const int col = wn * 128 + nt * 16 + lhi * 4;
                    *reinterpret_cast<f32x4*>(&eb[lr * 260 + col]) = acc[mt][nt];
                }
            }
        }
        __syncthreads();
        #pragma unroll
        for (int i = 0; i < 8; ++i) {
            const int lr = wid * 8 + i;
            f32x4 v = *reinterpret_cast<const f32x4*>(&eb[lr * 260 + lane * 4]) + b2v;
            float* p = out + (size_t)(row0 + c * 32 + lr) * ORS + (f + 1) * D_ + lane * 4;
            __builtin_nontemporal_store(v, reinterpret_cast<f32x4*>(p));
        }
        __syncthreads();
    }
}

// cls row: out[b][0][:] = cls_token (nontemporal)
__global__ void femb_cls(const float* __restrict__ cls, float* __restrict__ out)
{
    int i = blockIdx.x * 256 + threadIdx.x;
    int b = i >> 6;
    int q = i & 63;
    f32x4 v = *reinterpret_cast<const f32x4*>(cls + q * 4);
    __builtin_nontemporal_store(v, reinterpret_cast<f32x4*>(out + (size_t)b * ORS + q * 4));
}

// ---------------------------------------------------------------------------
// Fallback (round-2 main, proven): only if ws_size too small for W2t.
// ---------------------------------------------------------------------------
__global__ __launch_bounds__(256, 2) void femb_main_fb(
    const float* __restrict__ x,  const float* __restrict__ W1,
    const float* __restrict__ b1, const float* __restrict__ W2,
    const float* __restrict__ b2, float* __restrict__ out)
{
    __shared__ float w1s[D_];
    __shared__ float b1s[D_];
    __shared__ float xs[128];
    __shared__ __align__(16) unsigned short bW[256][72];

    const int tid  = threadIdx.x;
    const int bid  = blockIdx.x;
    const int f    = bid & 63;
    const int row0 = (bid >> 6) << 7;

    w1s[tid] = W1[f * D_ + tid];
    b1s[tid] = b1[f * D_ + tid];
    if (tid < 128) xs[tid] = x[(size_t)(row0 + tid) * F_ + f];

    const int lane = tid & 63;
    const int wid  = tid >> 6;
    const int wm   = wid >> 1;
    const int wn   = wid & 1;
    const int llo  = lane & 15;
    const int lhi  = lane >> 4;

    __syncthreads();

    float xv[4];
    #pragma unroll
    for (int mt = 0; mt < 4; ++mt) xv[mt] = xs[wm * 64 + mt * 16 + llo];

    f32x4 acc[4][8];
    #pragma unroll
    for (int mt = 0; mt < 4; ++mt)
        #pragma unroll
        for (int nt = 0; nt < 8; ++nt)
            acc[mt][nt] = (f32x4){0.f, 0.f, 0.f, 0.f};

    const float* w2col = W2 + (size_t)f * D_ * D_ + tid;

    for (int kb = 0; kb < 4; ++kb) {
        float r[64];
        const float* p = w2col + (size_t)(kb * 64) * D_;
        #pragma unroll
        for (int j = 0; j < 64; ++j) r[j] = p[(size_t)j * D_];

        __syncthreads();
        #pragma unroll
        for (int j8 = 0; j8 < 8; ++j8) {
            union { s16x8 s; unsigned short u[8]; } pk;
            #pragma unroll
            for (int e = 0; e < 8; ++e) pk.u[e] = to_bf16_bits(r[j8 * 8 + e]);
            *reinterpret_cast<s16x8*>(&bW[tid][j8 * 8]) = pk.s;
        }
        __syncthreads();

        #pragma unroll
        for (int ks = 0; ks < 2; ++ks) {
            const int kg = kb * 64 + ks * 32 + lhi * 8;
            float w1r[8], b1r[8];
            #pragma unroll
            for (int e = 0; e < 8; ++e) { w1r[e] = w1s[kg + e]; b1r[e] = b1s[kg + e]; }

            s16x8 afrag[4];
            #pragma unroll
            for (int mt = 0; mt < 4; ++mt) {
                union { s16x8 s; unsigned short u[8]; } pk;
                #pragma unroll
                for (int e = 0; e < 8; ++e) {
                    float h = fmaf(xv[mt], w1r[e], b1r[e]);
                    pk.u[e] = to_bf16_bits(fmaxf(h, 0.f));
                }
                afrag[mt] = pk.s;
            }

            const int kl = ks * 32 + lhi * 8;
            #pragma unroll
            for (int nt = 0; nt < 8; ++nt) {
                s16x8 bfrag = *reinterpret_cast<const s16x8*>(
                    &bW[wn * 128 + nt * 16 + llo][kl]);
                #pragma unroll
                for (int mt = 0; mt < 4; ++mt)
                    acc[mt][nt] = __builtin_amdgcn_mfma_f32_16x16x32_bf16(
                        bfrag, afrag[mt], acc[mt][nt], 0, 0, 0);
            }
        }
    }

    const float* b2f = b2 + f * D_;
    float* obase = out + (size_t)(row0 + wm * 64 + llo) * ORS
                       + (f + 1) * D_ + wn * 128 + lhi * 4;
    #pragma unroll
    for (int nt = 0; nt < 8; ++nt) {
        f32x4 bv = *reinterpret_cast<const f32x4*>(&b2f[wn * 128 + nt * 16 + lhi * 4]);
        #pragma unroll
        for (int mt = 0; mt < 4; ++mt) {
            f32x4 v = acc[mt][nt] + bv;
            *reinterpret_cast<f32x4*>(obase + (size_t)mt * 16 * ORS + nt * 16) = v;
        }
    }
}

extern "C" void kernel_launch(void* const* d_in, const int* in_sizes, int n_in,
                              void* d_out, int out_size, void* d_ws, size_t ws_size,
                              hipStream_t stream)
{
    const float* x   = (const float*)d_in[0];
    const float* W1  = (const float*)d_in[1];
    const float* b1  = (const float*)d_in[2];
    const float* W2  = (const float*)d_in[3];
    const float* b2  = (const float*)d_in[4];
    const float* cls = (const float*)d_in[5];
    float* out = (float*)d_out;

    femb_cls<<<(B_ * 64) / 256, 256, 0, stream>>>(cls, out);

    const size_t need = (size_t)F_ * D_ * D_ * sizeof(unsigned short); // 8 MiB
    if (ws_size >= need) {
        unsigned short* W2t = (unsigned short*)d_ws;
        femb_prep<<<F_ * 4, 256, 0, stream>>>(W2, W2t);
        femb_main3<<<F_ * (B_ / 64), 256, 0, stream>>>(x, W1, b1, W2t, b2, out);
    } else {
        femb_main_fb<<<F_ * (B_ / 128), 256, 0, stream>>>(x, W1, b1, W2, b2, out);
    }
}

// Round 4
// 79.147 us; speedup vs baseline: 2.0358x; 2.0358x over previous
//
#include <hip/hip_runtime.h>
#include <hip/hip_bf16.h>

// FeatureEmbedding: out[b, f+1, e] = sum_d relu(x[b,f]*W1[f,d]+b1[f,d]) * W2[f,d,e] + b2[f,e]
//                   out[b, 0,   e] = cls_token[e]
// B=4096, F=64, D=256. Output f32 [4096][65][256].

#define B_  4096
#define F_  64
#define D_  256
#define ORS (65 * 256)   // out row stride (floats)

using f32x4  = __attribute__((ext_vector_type(4))) float;
using s16x8  = __attribute__((ext_vector_type(8))) short;
typedef unsigned int u32;

__device__ __forceinline__ unsigned short to_bf16_bits(float v) {
    __hip_bfloat16 h = __float2bfloat16(v);
    return *reinterpret_cast<unsigned short*>(&h);
}

__device__ __forceinline__ void gload_lds16(const void* g, void* l) {
    __builtin_amdgcn_global_load_lds(
        (const __attribute__((address_space(1))) u32*)g,
        (__attribute__((address_space(3))) u32*)l, 16, 0, 0);
}

// ---------------------------------------------------------------------------
// Prep (proven round-2): W2 f32 [f][k][e] -> W2s bf16 [f][kb][n=e][p], p a 16B
// unit of 8 k, pre-swizzled p = j ^ (n&7). Linear LDS copy of a 32KB block IS
// the swizzled tile (rule 21: inverse-swizzled source + swizzled read).
// ---------------------------------------------------------------------------
__global__ __launch_bounds__(256) void femb_prep(
    const float* __restrict__ W2, unsigned short* __restrict__ W2s)
{
    const int blk = blockIdx.x;        // f*4 + kb
    const int f   = blk >> 2;
    const int kb  = blk & 3;
    const int t   = threadIdx.x;       // owns output column n = t

    const float* col = W2 + (size_t)f * D_ * D_ + (size_t)(kb * 64) * D_ + t;
    float r[64];
    #pragma unroll
    for (int j = 0; j < 64; ++j) r[j] = col[(size_t)j * D_];

    unsigned short* ob = W2s + (size_t)blk * 16384 + t * 64;
    #pragma unroll
    for (int j8 = 0; j8 < 8; ++j8) {
        union { s16x8 s; unsigned short u[8]; } pk;
        #pragma unroll
        for (int e = 0; e < 8; ++e) pk.u[e] = to_bf16_bits(r[j8 * 8 + e]);
        *reinterpret_cast<s16x8*>(ob + ((j8 ^ (t & 7)) * 8)) = pk.s;
    }
}

// ---------------------------------------------------------------------------
// Main: one block = (feature, 128-row tile). 256 threads = 4 waves (2x2).
// K-loop: double-buffered global_load_lds staging (issue next tile BEFORE
// computing current -> the __syncthreads vmcnt drain overlaps compute).
// Epilogue: transpose through LDS (reusing the staging arena) so each wave
// store instruction writes one contiguous 1KB output row. Normal stores.
// f==0 blocks also write the cls row (saves a dispatch).
// ---------------------------------------------------------------------------
__global__ __launch_bounds__(256, 2) void femb_main4(
    const float* __restrict__ x,  const float* __restrict__ W1,
    const float* __restrict__ b1, const unsigned short* __restrict__ W2s,
    const float* __restrict__ b2, const float* __restrict__ cls,
    float* __restrict__ out)
{
    __shared__ float w1s[D_];
    __shared__ float b1s[D_];
    __shared__ float xs[128];
    // K-loop: two 32KB bf16 tiles. Epilogue: 32 x 260 f32 (33.3KB) reuse.
    __shared__ __align__(16) char arena[65536];
    unsigned short* bW0 = (unsigned short*)arena;
    unsigned short* bW1 = (unsigned short*)(arena + 32768);
    float* eb = (float*)arena;

    const int tid  = threadIdx.x;
    const int bid  = blockIdx.x;
    const int f    = bid & 63;        // same-f blocks -> same bid%8 -> same XCD
    const int row0 = (bid >> 6) << 7; // 16 row-tiles of 128

    w1s[tid] = W1[f * D_ + tid];
    b1s[tid] = b1[f * D_ + tid];
    if (tid < 128) xs[tid] = x[(size_t)(row0 + tid) * F_ + f];

    const int lane = tid & 63;
    const int wid  = tid >> 6;
    const int wm   = wid >> 1;   // row half (64 rows)
    const int wn   = wid & 1;    // col half (128 cols)
    const int llo  = lane & 15;
    const int lhi  = lane >> 4;

    const char* gsrc = (const char*)(W2s + (size_t)f * 65536); // 4 tiles * 32 KB
    f32x4 clsv = *reinterpret_cast<const f32x4*>(cls + lane * 4);

#define STAGE(DST, KB)                                                         \
    {                                                                          \
        const char* gt = gsrc + (KB) * 32768;                                  \
        _Pragma("unroll")                                                      \
        for (int r = 0; r < 8; ++r)                                            \
            gload_lds16(gt + tid * 16 + r * 4096,                              \
                        (char*)(DST) + tid * 16 + r * 4096);                   \
    }

    STAGE(bW0, 0);
    __syncthreads();

    float xv[4];
    #pragma unroll
    for (int mt = 0; mt < 4; ++mt) xv[mt] = xs[wm * 64 + mt * 16 + llo];

    f32x4 acc[4][8];
    #pragma unroll
    for (int mt = 0; mt < 4; ++mt)
        #pragma unroll
        for (int nt = 0; nt < 8; ++nt)
            acc[mt][nt] = (f32x4){0.f, 0.f, 0.f, 0.f};

    #pragma unroll
    for (int kb = 0; kb < 4; ++kb) {
        unsigned short* cur = (kb & 1) ? bW1 : bW0;
        unsigned short* nxt = (kb & 1) ? bW0 : bW1;
        if (kb < 3) STAGE(nxt, kb + 1);   // fire async; drained by end barrier

        #pragma unroll
        for (int ks = 0; ks < 2; ++ks) {
            const int kg = kb * 64 + ks * 32 + lhi * 8;
            float w1r[8], b1r[8];
            #pragma unroll
            for (int e = 0; e < 8; ++e) { w1r[e] = w1s[kg + e]; b1r[e] = b1s[kg + e]; }

            s16x8 afrag[4];
            #pragma unroll
            for (int mt = 0; mt < 4; ++mt) {
                union { s16x8 s; unsigned short u[8]; } pk;
                #pragma unroll
                for (int e = 0; e < 8; ++e) {
                    float h = fmaf(xv[mt], w1r[e], b1r[e]);
                    pk.u[e] = to_bf16_bits(fmaxf(h, 0.f));
                }
                afrag[mt] = pk.s;
            }

            // n = wn*128 + nt*16 + llo; logical slot j = ks*4+lhi;
            // physical p = j ^ (llo&7)
            const int base16 = (wn * 128 + llo) * 64 + (((ks * 4 + lhi) ^ (llo & 7)) * 8);
            #pragma unroll
            for (int nt = 0; nt < 8; ++nt) {
                s16x8 bfrag = *reinterpret_cast<const s16x8*>(&cur[base16 + nt * 1024]);
                #pragma unroll
                for (int mt = 0; mt < 4; ++mt)
                    acc[mt][nt] = __builtin_amdgcn_mfma_f32_16x16x32_bf16(
                        bfrag, afrag[mt], acc[mt][nt], 0, 0, 0);
            }
        }
        __syncthreads();  // drains nxt's loads (overlapped with COMP) + read/write fence
    }

    // ---- Epilogue: 4 chunks of 32 rows through LDS; 1KB contiguous stores ----
    // acc layout (verified): row = wm*64 + mt*16 + llo ; col = wn*128 + nt*16 + lhi*4 + r
    f32x4 b2v = *reinterpret_cast<const f32x4*>(&b2[f * D_ + lane * 4]);

    #pragma unroll
    for (int c = 0; c < 4; ++c) {
        if (wm == (c >> 1)) {
            #pragma unroll
            for (int mi = 0; mi < 2; ++mi) {
                const int mt = (c & 1) * 2 + mi;
                const int lr = mi * 16 + llo;          // 0..31 within chunk
                #pragma unroll
                for (int nt = 0; nt < 8; ++nt)
                    *reinterpret_cast<f32x4*>(
                        &eb[lr * 260 + wn * 128 + nt * 16 + lhi * 4]) = acc[mt][nt];
            }
        }
        __syncthreads();
        #pragma unroll
        for (int i = 0; i < 8; ++i) {
            const int lr = wid * 8 + i;
            const size_t grow = (size_t)(row0 + c * 32 + lr);
            f32x4 v = *reinterpret_cast<const f32x4*>(&eb[lr * 260 + lane * 4]) + b2v;
            *reinterpret_cast<f32x4*>(out + grow * ORS + (f + 1) * D_ + lane * 4) = v;
            if (f == 0)
                *reinterpret_cast<f32x4*>(out + grow * ORS + lane * 4) = clsv;
        }
        __syncthreads();
    }
}

// ---------------------------------------------------------------------------
// Fallback path (round-1, proven) if ws too small: cls kernel + direct main.
// ---------------------------------------------------------------------------
__global__ void femb_cls(const float* __restrict__ cls, float* __restrict__ out)
{
    int i = blockIdx.x * 256 + threadIdx.x;
    int b = i >> 6;
    int q = i & 63;
    f32x4 v = *reinterpret_cast<const f32x4*>(cls + q * 4);
    *reinterpret_cast<f32x4*>(out + (size_t)b * ORS + q * 4) = v;
}

__global__ __launch_bounds__(256, 2) void femb_main_fb(
    const float* __restrict__ x,  const float* __restrict__ W1,
    const float* __restrict__ b1, const float* __restrict__ W2,
    const float* __restrict__ b2, float* __restrict__ out)
{
    __shared__ float w1s[D_];
    __shared__ float b1s[D_];
    __shared__ float xs[128];
    __shared__ __align__(16) unsigned short bW[256][72];

    const int tid  = threadIdx.x;
    const int bid  = blockIdx.x;
    const int f    = bid & 63;
    const int row0 = (bid >> 6) << 7;

    w1s[tid] = W1[f * D_ + tid];
    b1s[tid] = b1[f * D_ + tid];
    if (tid < 128) xs[tid] = x[(size_t)(row0 + tid) * F_ + f];

    const int lane = tid & 63;
    const int wid  = tid >> 6;
    const int wm   = wid >> 1;
    const int wn   = wid & 1;
    const int llo  = lane & 15;
    const int lhi  = lane >> 4;

    __syncthreads();

    float xv[4];
    #pragma unroll
    for (int mt = 0; mt < 4; ++mt) xv[mt] = xs[wm * 64 + mt * 16 + llo];

    f32x4 acc[4][8];
    #pragma unroll
    for (int mt = 0; mt < 4; ++mt)
        #pragma unroll
        for (int nt = 0; nt < 8; ++nt)
            acc[mt][nt] = (f32x4){0.f, 0.f, 0.f, 0.f};

    const float* w2col = W2 + (size_t)f * D_ * D_ + tid;

    for (int kb = 0; kb < 4; ++kb) {
        float r[64];
        const float* p = w2col + (size_t)(kb * 64) * D_;
        #pragma unroll
        for (int j = 0; j < 64; ++j) r[j] = p[(size_t)j * D_];

        __syncthreads();
        #pragma unroll
        for (int j8 = 0; j8 < 8; ++j8) {
            union { s16x8 s; unsigned short u[8]; } pk;
            #pragma unroll
            for (int e = 0; e < 8; ++e) pk.u[e] = to_bf16_bits(r[j8 * 8 + e]);
            *reinterpret_cast<s16x8*>(&bW[tid][j8 * 8]) = pk.s;
        }
        __syncthreads();

        #pragma unroll
        for (int ks = 0; ks < 2; ++ks) {
            const int kg = kb * 64 + ks * 32 + lhi * 8;
            float w1r[8], b1r[8];
            #pragma unroll
            for (int e = 0; e < 8; ++e) { w1r[e] = w1s[kg + e]; b1r[e] = b1s[kg + e]; }

            s16x8 afrag[4];
            #pragma unroll
            for (int mt = 0; mt < 4; ++mt) {
                union { s16x8 s; unsigned short u[8]; } pk;
                #pragma unroll
                for (int e = 0; e < 8; ++e) {
                    float h = fmaf(xv[mt], w1r[e], b1r[e]);
                    pk.u[e] = to_bf16_bits(fmaxf(h, 0.f));
                }
                afrag[mt] = pk.s;
            }

            const int kl = ks * 32 + lhi * 8;
            #pragma unroll
            for (int nt = 0; nt < 8; ++nt) {
                s16x8 bfrag = *reinterpret_cast<const s16x8*>(
                    &bW[wn * 128 + nt * 16 + llo][kl]);
                #pragma unroll
                for (int mt = 0; mt < 4; ++mt)
                    acc[mt][nt] = __builtin_amdgcn_mfma_f32_16x16x32_bf16(
                        bfrag, afrag[mt], acc[mt][nt], 0, 0, 0);
            }
        }
    }

    const float* b2f = b2 + f * D_;
    float* obase = out + (size_t)(row0 + wm * 64 + llo) * ORS
                       + (f + 1) * D_ + wn * 128 + lhi * 4;
    #pragma unroll
    for (int nt = 0; nt < 8; ++nt) {
        f32x4 bv = *reinterpret_cast<const f32x4*>(&b2f[wn * 128 + nt * 16 + lhi * 4]);
        #pragma unroll
        for (int mt = 0; mt < 4; ++mt) {
            f32x4 v = acc[mt][nt] + bv;
            *reinterpret_cast<f32x4*>(obase + (size_t)mt * 16 * ORS + nt * 16) = v;
        }
    }
}

extern "C" void kernel_launch(void* const* d_in, const int* in_sizes, int n_in,
                              void* d_out, int out_size, void* d_ws, size_t ws_size,
                              hipStream_t stream)
{
    const float* x   = (const float*)d_in[0];
    const float* W1  = (const float*)d_in[1];
    const float* b1  = (const float*)d_in[2];
    const float* W2  = (const float*)d_in[3];
    const float* b2  = (const float*)d_in[4];
    const float* cls = (const float*)d_in[5];
    float* out = (float*)d_out;

    const size_t need = (size_t)F_ * D_ * D_ * sizeof(unsigned short); // 8 MiB
    if (ws_size >= need) {
        unsigned short* W2s = (unsigned short*)d_ws;
        femb_prep<<<F_ * 4, 256, 0, stream>>>(W2, W2s);
        femb_main4<<<F_ * (B_ / 128), 256, 0, stream>>>(x, W1, b1, W2s, b2, cls, out);
    } else {
        femb_cls<<<(B_ * 64) / 256, 256, 0, stream>>>(cls, out);
        femb_main_fb<<<F_ * (B_ / 128), 256, 0, stream>>>(x, W1, b1, W2, b2, out);
    }
}

// Round 5
// 78.282 us; speedup vs baseline: 2.0583x; 1.0111x over previous
//
#include <hip/hip_runtime.h>
#include <hip/hip_bf16.h>

// FeatureEmbedding: out[b, f+1, e] = sum_d relu(x[b,f]*W1[f,d]+b1[f,d]) * W2[f,d,e] + b2[f,e]
//                   out[b, 0,   e] = cls_token[e]
// B=4096, F=64, D=256. Output f32 [4096][65][256].

#define B_  4096
#define F_  64
#define D_  256
#define ORS (65 * 256)   // out row stride (floats)

using f32x4  = __attribute__((ext_vector_type(4))) float;
using s16x8  = __attribute__((ext_vector_type(8))) short;
typedef unsigned int u32;

__device__ __forceinline__ unsigned short to_bf16_bits(float v) {
    __hip_bfloat16 h = __float2bfloat16(v);
    return *reinterpret_cast<unsigned short*>(&h);
}

__device__ __forceinline__ void gload_lds16(const void* g, void* l) {
    __builtin_amdgcn_global_load_lds(
        (const __attribute__((address_space(1))) u32*)g,
        (__attribute__((address_space(3))) u32*)l, 16, 0, 0);
}

// ---------------------------------------------------------------------------
// Prep (proven): W2 f32 [f][k][e] -> W2s bf16 [f][kb][n=e][p], p a 16B unit of
// 8 k, pre-swizzled p = j ^ (n&7). Linear LDS copy of a 32KB block IS the
// swizzled tile (rule 21: inverse-swizzled source + swizzled read).
// ---------------------------------------------------------------------------
__global__ __launch_bounds__(256) void femb_prep(
    const float* __restrict__ W2, unsigned short* __restrict__ W2s)
{
    const int blk = blockIdx.x;        // f*4 + kb
    const int f   = blk >> 2;
    const int kb  = blk & 3;
    const int t   = threadIdx.x;       // owns output column n = t

    const float* col = W2 + (size_t)f * D_ * D_ + (size_t)(kb * 64) * D_ + t;
    float r[64];
    #pragma unroll
    for (int j = 0; j < 64; ++j) r[j] = col[(size_t)j * D_];

    unsigned short* ob = W2s + (size_t)blk * 16384 + t * 64;
    #pragma unroll
    for (int j8 = 0; j8 < 8; ++j8) {
        union { s16x8 s; unsigned short u[8]; } pk;
        #pragma unroll
        for (int e = 0; e < 8; ++e) pk.u[e] = to_bf16_bits(r[j8 * 8 + e]);
        *reinterpret_cast<s16x8*>(ob + ((j8 ^ (t & 7)) * 8)) = pk.s;
    }
}

// ---------------------------------------------------------------------------
// Main: one block = (feature, 128-row tile). 256 threads = 4 waves (2x2).
// K-loop: double-buffered global_load_lds (issue next tile BEFORE compute).
// Epilogue: 8 ping-pong 16-row LDS-transpose chunks with lgkmcnt-ONLY raw
// barriers -> global stores are NEVER vmcnt-drained inside the kernel; they
// stream continuously to HBM while LDS phases run. Each store = 1KB row.
// f==0 blocks also write the cls row.
// ---------------------------------------------------------------------------
__global__ __launch_bounds__(256, 2) void femb_main5(
    const float* __restrict__ x,  const float* __restrict__ W1,
    const float* __restrict__ b1, const unsigned short* __restrict__ W2s,
    const float* __restrict__ b2, const float* __restrict__ cls,
    float* __restrict__ out)
{
    __shared__ float w1s[D_];
    __shared__ float b1s[D_];
    __shared__ float xs[128];
    // K-loop: two 32KB bf16 tiles. Epilogue: two 16x260 f32 buffers (16.6KB ea).
    __shared__ __align__(16) char arena[65536];
    unsigned short* bW0 = (unsigned short*)arena;
    unsigned short* bW1 = (unsigned short*)(arena + 32768);
    float* eb0 = (float*)arena;
    float* eb1 = (float*)(arena + 16640);   // 16*260*4 bytes

    const int tid  = threadIdx.x;
    const int bid  = blockIdx.x;
    const int f    = bid & 63;        // same-f blocks -> same bid%8 -> same XCD
    const int row0 = (bid >> 6) << 7;

    w1s[tid] = W1[f * D_ + tid];
    b1s[tid] = b1[f * D_ + tid];
    if (tid < 128) xs[tid] = x[(size_t)(row0 + tid) * F_ + f];

    const int lane = tid & 63;
    const int wid  = tid >> 6;
    const int wm   = wid >> 1;   // row half (64 rows)
    const int wn   = wid & 1;    // col half (128 cols)
    const int llo  = lane & 15;
    const int lhi  = lane >> 4;

    const char* gsrc = (const char*)(W2s + (size_t)f * 65536);
    f32x4 clsv = *reinterpret_cast<const f32x4*>(cls + lane * 4);

#define STAGE(DST, KB)                                                         \
    {                                                                          \
        const char* gt = gsrc + (KB) * 32768;                                  \
        _Pragma("unroll")                                                      \
        for (int r = 0; r < 8; ++r)                                            \
            gload_lds16(gt + tid * 16 + r * 4096,                              \
                        (char*)(DST) + tid * 16 + r * 4096);                   \
    }

    STAGE(bW0, 0);
    __syncthreads();

    float xv[4];
    #pragma unroll
    for (int mt = 0; mt < 4; ++mt) xv[mt] = xs[wm * 64 + mt * 16 + llo];

    f32x4 acc[4][8];
    #pragma unroll
    for (int mt = 0; mt < 4; ++mt)
        #pragma unroll
        for (int nt = 0; nt < 8; ++nt)
            acc[mt][nt] = (f32x4){0.f, 0.f, 0.f, 0.f};

    #pragma unroll
    for (int kb = 0; kb < 4; ++kb) {
        unsigned short* cur = (kb & 1) ? bW1 : bW0;
        unsigned short* nxt = (kb & 1) ? bW0 : bW1;
        if (kb < 3) STAGE(nxt, kb + 1);   // async; drained by end-of-iter barrier

        #pragma unroll
        for (int ks = 0; ks < 2; ++ks) {
            const int kg = kb * 64 + ks * 32 + lhi * 8;
            float w1r[8], b1r[8];
            #pragma unroll
            for (int e = 0; e < 8; ++e) { w1r[e] = w1s[kg + e]; b1r[e] = b1s[kg + e]; }

            s16x8 afrag[4];
            #pragma unroll
            for (int mt = 0; mt < 4; ++mt) {
                union { s16x8 s; unsigned short u[8]; } pk;
                #pragma unroll
                for (int e = 0; e < 8; ++e) {
                    float h = fmaf(xv[mt], w1r[e], b1r[e]);
                    pk.u[e] = to_bf16_bits(fmaxf(h, 0.f));
                }
                afrag[mt] = pk.s;
            }

            // n = wn*128 + nt*16 + llo; logical slot j = ks*4+lhi; p = j ^ (llo&7)
            const int base16 = (wn * 128 + llo) * 64 + (((ks * 4 + lhi) ^ (llo & 7)) * 8);
            #pragma unroll
            for (int nt = 0; nt < 8; ++nt) {
                s16x8 bfrag = *reinterpret_cast<const s16x8*>(&cur[base16 + nt * 1024]);
                #pragma unroll
                for (int mt = 0; mt < 4; ++mt)
                    acc[mt][nt] = __builtin_amdgcn_mfma_f32_16x16x32_bf16(
                        bfrag, afrag[mt], acc[mt][nt], 0, 0, 0);
            }
        }
        __syncthreads();  // vmcnt drain: next tile ready; also fences bW reuse
    }

    // ---- Epilogue: 8 ping-pong chunks of 16 rows; stores never drained ----
    // acc layout: row = wm*64 + mt*16 + llo ; col = wn*128 + nt*16 + lhi*4 + r.
    // Chunk c covers rows [16c,16c+16): written by waves with wm==c>>2, mt=c&3.
    f32x4 b2v = *reinterpret_cast<const f32x4*>(&b2[f * D_ + lane * 4]);

#define EPI_WRITE(C, EB)                                                       \
    if (wm == ((C) >> 2)) {                                                    \
        const int mt_ = (C) & 3;                                               \
        _Pragma("unroll")                                                      \
        for (int nt = 0; nt < 8; ++nt)                                         \
            *reinterpret_cast<f32x4*>(                                         \
                &(EB)[llo * 260 + wn * 128 + nt * 16 + lhi * 4]) = acc[mt_][nt]; \
    }

    // lgkmcnt-only barrier: LDS ordering without draining global stores.
#define EPI_BAR()                                                              \
    do {                                                                       \
        asm volatile("s_waitcnt lgkmcnt(0)" ::: "memory");                     \
        __builtin_amdgcn_s_barrier();                                          \
        asm volatile("" ::: "memory");                                         \
    } while (0)

#define EPI_READ(C, EB)                                                        \
    {                                                                          \
        _Pragma("unroll")                                                      \
        for (int i = 0; i < 4; ++i) {                                          \
            const int lr = wid * 4 + i;                                        \
            const size_t grow = (size_t)(row0 + (C) * 16 + lr);                \
            f32x4 v = *reinterpret_cast<const f32x4*>(                         \
                          &(EB)[lr * 260 + lane * 4]) + b2v;                   \
            *reinterpret_cast<f32x4*>(out + grow * ORS + (f + 1) * D_ + lane * 4) = v; \
            if (f == 0)                                                        \
                *reinterpret_cast<f32x4*>(out + grow * ORS + lane * 4) = clsv; \
        }                                                                      \
    }

    EPI_WRITE(0, eb0);
    EPI_BAR();
    #pragma unroll
    for (int c = 0; c < 8; ++c) {
        float* curb = (c & 1) ? eb1 : eb0;
        float* nxtb = (c & 1) ? eb0 : eb1;
        if (c < 7) EPI_WRITE(c + 1, nxtb);
        EPI_READ(c, curb);
        if (c < 7) EPI_BAR();
    }
#undef STAGE
#undef EPI_WRITE
#undef EPI_BAR
#undef EPI_READ
}

// ---------------------------------------------------------------------------
// Fallback path (round-1, proven) if ws too small: cls kernel + direct main.
// ---------------------------------------------------------------------------
__global__ void femb_cls(const float* __restrict__ cls, float* __restrict__ out)
{
    int i = blockIdx.x * 256 + threadIdx.x;
    int b = i >> 6;
    int q = i & 63;
    f32x4 v = *reinterpret_cast<const f32x4*>(cls + q * 4);
    *reinterpret_cast<f32x4*>(out + (size_t)b * ORS + q * 4) = v;
}

__global__ __launch_bounds__(256, 2) void femb_main_fb(
    const float* __restrict__ x,  const float* __restrict__ W1,
    const float* __restrict__ b1, const float* __restrict__ W2,
    const float* __restrict__ b2, float* __restrict__ out)
{
    __shared__ float w1s[D_];
    __shared__ float b1s[D_];
    __shared__ float xs[128];
    __shared__ __align__(16) unsigned short bW[256][72];

    const int tid  = threadIdx.x;
    const int bid  = blockIdx.x;
    const int f    = bid & 63;
    const int row0 = (bid >> 6) << 7;

    w1s[tid] = W1[f * D_ + tid];
    b1s[tid] = b1[f * D_ + tid];
    if (tid < 128) xs[tid] = x[(size_t)(row0 + tid) * F_ + f];

    const int lane = tid & 63;
    const int wid  = tid >> 6;
    const int wm   = wid >> 1;
    const int wn   = wid & 1;
    const int llo  = lane & 15;
    const int lhi  = lane >> 4;

    __syncthreads();

    float xv[4];
    #pragma unroll
    for (int mt = 0; mt < 4; ++mt) xv[mt] = xs[wm * 64 + mt * 16 + llo];

    f32x4 acc[4][8];
    #pragma unroll
    for (int mt = 0; mt < 4; ++mt)
        #pragma unroll
        for (int nt = 0; nt < 8; ++nt)
            acc[mt][nt] = (f32x4){0.f, 0.f, 0.f, 0.f};

    const float* w2col = W2 + (size_t)f * D_ * D_ + tid;

    for (int kb = 0; kb < 4; ++kb) {
        float r[64];
        const float* p = w2col + (size_t)(kb * 64) * D_;
        #pragma unroll
        for (int j = 0; j < 64; ++j) r[j] = p[(size_t)j * D_];

        __syncthreads();
        #pragma unroll
        for (int j8 = 0; j8 < 8; ++j8) {
            union { s16x8 s; unsigned short u[8]; } pk;
            #pragma unroll
            for (int e = 0; e < 8; ++e) pk.u[e] = to_bf16_bits(r[j8 * 8 + e]);
            *reinterpret_cast<s16x8*>(&bW[tid][j8 * 8]) = pk.s;
        }
        __syncthreads();

        #pragma unroll
        for (int ks = 0; ks < 2; ++ks) {
            const int kg = kb * 64 + ks * 32 + lhi * 8;
            float w1r[8], b1r[8];
            #pragma unroll
            for (int e = 0; e < 8; ++e) { w1r[e] = w1s[kg + e]; b1r[e] = b1s[kg + e]; }

            s16x8 afrag[4];
            #pragma unroll
            for (int mt = 0; mt < 4; ++mt) {
                union { s16x8 s; unsigned short u[8]; } pk;
                #pragma unroll
                for (int e = 0; e < 8; ++e) {
                    float h = fmaf(xv[mt], w1r[e], b1r[e]);
                    pk.u[e] = to_bf16_bits(fmaxf(h, 0.f));
                }
                afrag[mt] = pk.s;
            }

            const int kl = ks * 32 + lhi * 8;
            #pragma unroll
            for (int nt = 0; nt < 8; ++nt) {
                s16x8 bfrag = *reinterpret_cast<const s16x8*>(
                    &bW[wn * 128 + nt * 16 + llo][kl]);
                #pragma unroll
                for (int mt = 0; mt < 4; ++mt)
                    acc[mt][nt] = __builtin_amdgcn_mfma_f32_16x16x32_bf16(
                        bfrag, afrag[mt], acc[mt][nt], 0, 0, 0);
            }
        }
    }

    const float* b2f = b2 + f * D_;
    float* obase = out + (size_t)(row0 + wm * 64 + llo) * ORS
                       + (f + 1) * D_ + wn * 128 + lhi * 4;
    #pragma unroll
    for (int nt = 0; nt < 8; ++nt) {
        f32x4 bv = *reinterpret_cast<const f32x4*>(&b2f[wn * 128 + nt * 16 + lhi * 4]);
        #pragma unroll
        for (int mt = 0; mt < 4; ++mt) {
            f32x4 v = acc[mt][nt] + bv;
            *reinterpret_cast<f32x4*>(obase + (size_t)mt * 16 * ORS + nt * 16) = v;
        }
    }
}

extern "C" void kernel_launch(void* const* d_in, const int* in_sizes, int n_in,
                              void* d_out, int out_size, void* d_ws, size_t ws_size,
                              hipStream_t stream)
{
    const float* x   = (const float*)d_in[0];
    const float* W1  = (const float*)d_in[1];
    const float* b1  = (const float*)d_in[2];
    const float* W2  = (const float*)d_in[3];
    const float* b2  = (const float*)d_in[4];
    const float* cls = (const float*)d_in[5];
    float* out = (float*)d_out;

    const size_t need = (size_t)F_ * D_ * D_ * sizeof(unsigned short); // 8 MiB
    if (ws_size >= need) {
        unsigned short* W2s = (unsigned short*)d_ws;
        femb_prep<<<F_ * 4, 256, 0, stream>>>(W2, W2s);
        femb_main5<<<F_ * (B_ / 128), 256, 0, stream>>>(x, W1, b1, W2s, b2, cls, out);
    } else {
        femb_cls<<<(B_ * 64) / 256, 256, 0, stream>>>(cls, out);
        femb_main_fb<<<F_ * (B_ / 128), 256, 0, stream>>>(x, W1, b1, W2, b2, out);
    }
}